// Round 1
// baseline (1303.062 us; speedup 1.0000x reference)
//
#include <hip/hip_runtime.h>

#define N_PIXELS  65536
#define N_CENTERS 4096
#define BLOCK_THREADS 1024
#define WAVES_PER_BLOCK 16

// exp(-d2 / (2*SDP2)) = exp2(d2 * -log2(e)/8), SDP2 = 4.0
#define EXP2_COEF (-0.18033688011112042f)

__global__ __launch_bounds__(BLOCK_THREADS, 2) void kbpa_fused(
    const float* __restrict__ K,        // [N_PIXELS, N_CENTERS]
    const float* __restrict__ betas,    // [N_CENTERS, 2]
    const float* __restrict__ alphas,   // [N_CENTERS, 1]
    const float* __restrict__ pixels,   // [N_PIXELS, 2]
    const float* __restrict__ centers,  // [N_CENTERS, 2]
    float* __restrict__ out)            // [N_PIXELS]
{
    // 80 KB LDS -> 2 blocks/CU -> 32 waves/CU (full occupancy)
    __shared__ __align__(16) float  s_b0[N_CENTERS];
    __shared__ __align__(16) float  s_b1[N_CENTERS];
    __shared__ __align__(16) float2 s_c[N_CENTERS];
    __shared__ __align__(16) float  s_a[N_CENTERS];

    const int tid = threadIdx.x;

    // Cooperative staging: betas deinterleaved for conflict-free b128 reads.
    for (int i = tid; i < N_CENTERS; i += BLOCK_THREADS) {
        float2 b = ((const float2*)betas)[i];
        s_b0[i] = b.x;
        s_b1[i] = b.y;
        s_c[i]  = ((const float2*)centers)[i];
        s_a[i]  = alphas[i];
    }
    __syncthreads();

    const int wave  = tid >> 6;
    const int lane  = tid & 63;
    const int pixel = blockIdx.x * WAVES_PER_BLOCK + wave;

    // ---- Phase A: deformation[pixel] = K[pixel,:] @ betas  (memory-bound) ----
    const float4* Krow = (const float4*)(K + (size_t)pixel * N_CENTERS);
    float acc0 = 0.f, acc1 = 0.f;
    #pragma unroll
    for (int it = 0; it < 16; ++it) {
        const int col4 = it * 64 + lane;      // float4 index; 1 KB coalesced per wave-instr
        float4 k4 = Krow[col4];
        const int c = col4 * 4;
        float4 b0 = *(const float4*)(&s_b0[c]);
        float4 b1 = *(const float4*)(&s_b1[c]);
        acc0 += k4.x * b0.x + k4.y * b0.y + k4.z * b0.z + k4.w * b0.w;
        acc1 += k4.x * b1.x + k4.y * b1.y + k4.z * b1.z + k4.w * b1.w;
    }
    #pragma unroll
    for (int off = 1; off < 64; off <<= 1) {
        acc0 += __shfl_xor(acc0, off, 64);
        acc1 += __shfl_xor(acc1, off, 64);
    }

    const float2 pix = ((const float2*)pixels)[pixel];
    const float px = pix.x - acc0;
    const float py = pix.y - acc1;

    // ---- Phase B: out[pixel] = sum_j alpha[j] * exp(-||p - c_j||^2 / 8) ----
    float acc = 0.f;
    #pragma unroll 8
    for (int k = 0; k < 64; ++k) {
        const int j = k * 64 + lane;          // 8B lane stride: free 2-way aliasing
        const float2 c = s_c[j];
        const float  a = s_a[j];
        const float dx = px - c.x;
        const float dy = py - c.y;
        const float d2 = dx * dx + dy * dy;
        acc += a * __builtin_amdgcn_exp2f(d2 * EXP2_COEF);
    }
    #pragma unroll
    for (int off = 1; off < 64; off <<= 1)
        acc += __shfl_xor(acc, off, 64);

    if (lane == 0) out[pixel] = acc;
}

extern "C" void kernel_launch(void* const* d_in, const int* in_sizes, int n_in,
                              void* d_out, int out_size, void* d_ws, size_t ws_size,
                              hipStream_t stream) {
    const float* K       = (const float*)d_in[0];
    const float* betas   = (const float*)d_in[1];
    const float* alphas  = (const float*)d_in[2];
    const float* pixels  = (const float*)d_in[3];
    const float* centers = (const float*)d_in[4];
    float* out = (float*)d_out;

    dim3 grid(N_PIXELS / WAVES_PER_BLOCK);   // 4096 blocks
    dim3 block(BLOCK_THREADS);
    kbpa_fused<<<grid, block, 0, stream>>>(K, betas, alphas, pixels, centers, out);
}